// Round 8
// baseline (227.966 us; speedup 1.0000x reference)
//
#include <hip/hip_runtime.h>

typedef __bf16 bf16;
typedef __bf16 bf16x4 __attribute__((ext_vector_type(4)));
typedef __bf16 bf16x8 __attribute__((ext_vector_type(8)));
typedef float f32x4 __attribute__((ext_vector_type(4)));

#define T_LEN   4096
#define D_MODEL 1024
#define QKV_LD  1536
#define KDIM    1024   // K of both GEMMs (compile-time for full unroll)
#define VT_LD   4128   // 4096 + 32 pad: last tile's PV chunk over-reads into pad (x0 P)
#define WINDOW  256

// ---------------- fused prep: x->bf16, Wq|Wk|Wv transpose, Wo transpose -----
// grid sections: [0,2048) cvt, [2048,3584) wqkv, [3584,4608) wo

__global__ __launch_bounds__(256) void prep_fused(
    const float* __restrict__ x,
    const float* __restrict__ Wq, const float* __restrict__ Wk,
    const float* __restrict__ Wv, const float* __restrict__ Wo,
    bf16* __restrict__ xb, bf16* __restrict__ WtQKV, bf16* __restrict__ WtO)
{
    __shared__ float t[32][33];
    const int blk = blockIdx.x;
    if (blk < 2048) {                       // ---- x (f32) -> xb (bf16)
        int i = (blk * 256 + threadIdx.x) * 8;
        float4 a = *(const float4*)(x + i);
        float4 b = *(const float4*)(x + i + 4);
        bf16x8 o;
        o[0] = (bf16)a.x; o[1] = (bf16)a.y; o[2] = (bf16)a.z; o[3] = (bf16)a.w;
        o[4] = (bf16)b.x; o[5] = (bf16)b.y; o[6] = (bf16)b.z; o[7] = (bf16)b.w;
        *(bf16x8*)(xb + i) = o;
        return;
    }
    const float* W; bf16* Wt; int n0, k0, Ns, nofs;
    if (blk < 3584) {                       // ---- Wq|Wk|Wv -> WtQKV (1536x1024)
        int b = blk - 2048;
        n0 = (b % 48) * 32; k0 = (b / 48) * 32;
        if (n0 < 1024)      { W = Wq; Ns = 1024; nofs = 0; }
        else if (n0 < 1280) { W = Wk; Ns = 256;  nofs = 1024; }
        else                { W = Wv; Ns = 256;  nofs = 1280; }
        Wt = WtQKV;
    } else {                                // ---- Wo -> WtO (1024x1024)
        int b = blk - 3584;
        n0 = (b % 32) * 32; k0 = (b / 32) * 32;
        W = Wo; Ns = 1024; nofs = 0; Wt = WtO;
    }
    int tx = threadIdx.x & 31, ty = threadIdx.x >> 5;
#pragma unroll
    for (int it = 0; it < 4; ++it)
        t[ty + it * 8][tx] = W[(size_t)(k0 + ty + it * 8) * Ns + (n0 - nofs) + tx];
    __syncthreads();
#pragma unroll
    for (int it = 0; it < 4; ++it)
        Wt[(size_t)(n0 + ty + it * 8) * 1024 + k0 + tx] = (bf16)t[tx][ty + it * 8];
}

// ---------------- no-LDS register GEMM: C(MxN) = A(MxK)*Bt(NxK)^T + bias ----
// 4 waves (2x2) per block, block tile 128x128, wave tile 64x64.
// A/B MFMA fragments loaded DIRECTLY from global (each wave-load = 16 rows
// x 64 B segments, fully 64B-granular; same pattern as attn_kernel). No
// LDS, no barriers -> no vmcnt(0) drain, waves slip freely, compiler
// software-pipelines. Register double-buffer: prefetch kt+1 during kt's
// 16 MFMAs. XCD swizzle keeps each A-band L2-resident on its XCD.
// QKV_BIAS: col-blocks n0>=1280 are V -> written transposed to Vt.

template <bool OUT_BF16, bool QKV_BIAS>
__global__ __launch_bounds__(256) void gemm_bt(
    const bf16* __restrict__ A, const bf16* __restrict__ Bt,
    const float* __restrict__ b0, const float* __restrict__ b1,
    const float* __restrict__ b2, void* __restrict__ Cv, bf16* __restrict__ Vt,
    int M, int N, int nbx, int bands_per_xcd)
{
    const int blk = blockIdx.x;
    const int xcd = blk & 7;
    const int s   = blk >> 3;
    const int m0 = (xcd * bands_per_xcd + s / nbx) * 128;
    const int n0 = (s % nbx) * 128;
    const int tid  = threadIdx.x;
    const int wave = tid >> 6, lane = tid & 63;
    const int quad = lane >> 4, l16 = lane & 15;
    const int wm = wave >> 1, wn = wave & 1;

    f32x4 acc[4][4] = {};

    const bf16* pa = A  + (size_t)(m0 + wm * 64 + l16) * KDIM + quad * 8;
    const bf16* pb = Bt + (size_t)(n0 + wn * 64 + l16) * KDIM + quad * 8;

    bf16x8 af[2][4], bfr[2][4];
#pragma unroll
    for (int i = 0; i < 4; ++i) {
        af[0][i]  = *(const bf16x8*)(pa + i * 16 * KDIM);
        bfr[0][i] = *(const bf16x8*)(pb + i * 16 * KDIM);
    }

    const int nk = KDIM / 32;
#pragma unroll
    for (int kt = 0; kt < nk; ++kt) {
        const int cur = kt & 1, nxt = cur ^ 1;
        if (kt + 1 < nk) {
#pragma unroll
            for (int i = 0; i < 4; ++i) {
                af[nxt][i]  = *(const bf16x8*)(pa + i * 16 * KDIM + (kt + 1) * 32);
                bfr[nxt][i] = *(const bf16x8*)(pb + i * 16 * KDIM + (kt + 1) * 32);
            }
        }
#pragma unroll
        for (int i = 0; i < 4; ++i)
#pragma unroll
            for (int j = 0; j < 4; ++j)
                acc[i][j] = __builtin_amdgcn_mfma_f32_16x16x32_bf16(af[cur][i], bfr[cur][j], acc[i][j], 0, 0, 0);
    }

    const bool vtile = QKV_BIAS && (n0 >= 1280);
#pragma unroll
    for (int i = 0; i < 4; ++i)
#pragma unroll
        for (int j = 0; j < 4; ++j) {
            const int col = n0 + wn * 64 + j * 16 + l16;
            const float bb = QKV_BIAS
                ? (col < 1024 ? b0[col] : (col < 1280 ? b1[col - 1024] : b2[col - 1280]))
                : b0[col];
            const int row0 = m0 + wm * 64 + i * 16 + quad * 4;
            if (vtile) {
                bf16x4 pv;
#pragma unroll
                for (int r = 0; r < 4; ++r) pv[r] = (bf16)(acc[i][j][r] + bb);
                *(bf16x4*)&Vt[(size_t)(col - 1280) * VT_LD + row0] = pv;
            } else {
#pragma unroll
                for (int r = 0; r < 4; ++r) {
                    const float v = acc[i][j][r] + bb;
                    if (OUT_BF16) ((bf16*)Cv)[(size_t)(row0 + r) * N + col] = (bf16)v;
                    else          ((float*)Cv)[(size_t)(row0 + r) * N + col] = v;
                }
            }
        }
}

// ---------------- attention: 4 waves/block, 1 wave per (16-query tile, head) --
// Window <= 272 keys -> 17 S tiles of 16, PV over 9 K-chunks of 32.

__global__ __launch_bounds__(256) void attn_kernel(
    const bf16* __restrict__ QKV, const bf16* __restrict__ Vt, bf16* __restrict__ Oa)
{
    __shared__ bf16 Ps[4][16][296];   // per-wave P tile; 592 B rows: 2-way alias only
    const int wave = threadIdx.x >> 6;
    const int lane = threadIdx.x & 63;
    const int q0 = (blockIdx.x * 4 + wave) * 16;
    const int h  = blockIdx.y;
    const int kh = h >> 2;                     // GQA: head h -> kv head h/4
    const int quad = lane >> 4, l16 = lane & 15;
    const float slope = exp2f(-0.5f * (float)(h + 1));   // NH=16 ALiBi slopes
    const int lo = (q0 >= 256) ? (q0 - 256) : 0;          // window start

    // Q A-fragments (k-chunks 0 and 32 of HD=64)
    const bf16* qp = QKV + (size_t)(q0 + l16) * QKV_LD + h * 64 + quad * 8;
    bf16x8 qf0 = *(const bf16x8*)qp;
    bf16x8 qf1 = *(const bf16x8*)(qp + 32);

    // S = Q K^T : 17 tiles of 16 keys, fully unrolled so s[] stays in VGPRs
    f32x4 s[17];
#pragma unroll
    for (int t = 0; t < 17; ++t) {
        const bf16* kp = QKV + (size_t)(lo + t * 16 + l16) * QKV_LD + D_MODEL + kh * 64 + quad * 8;
        bf16x8 kf0 = *(const bf16x8*)kp;
        bf16x8 kf1 = *(const bf16x8*)(kp + 32);
        f32x4 a = {};
        a = __builtin_amdgcn_mfma_f32_16x16x32_bf16(qf0, kf0, a, 0, 0, 0);
        a = __builtin_amdgcn_mfma_f32_16x16x32_bf16(qf1, kf1, a, 0, 0, 0);
        s[t] = a;
    }

    // masked ALiBi softmax; lane holds rows quad*4+r at col l16 of each tile
    float rinv[4];
#pragma unroll
    for (int r = 0; r < 4; ++r) {
        const int row = q0 + quad * 4 + r;
        float mx = -1e30f;
#pragma unroll
        for (int t = 0; t < 17; ++t) {
            const int key = lo + t * 16 + l16;
            float v = s[t][r] * 0.125f - slope * (float)(row - key);
            const bool ok = (key <= row) && (key > row - WINDOW);
            v = ok ? v : -1e30f;
            s[t][r] = v;
            mx = fmaxf(mx, v);
        }
#pragma unroll
        for (int d = 1; d < 16; d <<= 1) mx = fmaxf(mx, __shfl_xor(mx, d));
        float sum = 0.f;
#pragma unroll
        for (int t = 0; t < 17; ++t) {
            float p = __expf(s[t][r] - mx);
            s[t][r] = p;
            sum += p;
        }
#pragma unroll
        for (int d = 1; d < 16; d <<= 1) sum += __shfl_xor(sum, d);
        rinv[r] = 1.f / sum;
    }

    // zero pad cols [272,288) (PV reads 288 cols)
    {
        int idx = lane;
#pragma unroll
        for (int it = 0; it < 4; ++it) {
            Ps[wave][(idx >> 4) & 15][272 + (idx & 15)] = (bf16)0.f;
            idx += 64;
        }
    }
    // P: C-layout regs -> LDS -> A-layout frags
#pragma unroll
    for (int t = 0; t < 17; ++t)
#pragma unroll
        for (int r = 0; r < 4; ++r)
            Ps[wave][quad * 4 + r][t * 16 + l16] = (bf16)(s[t][r] * rinv[r]);
    __syncthreads();

    // O = P V : V B-frags straight from global Vt (contiguous along keys)
    f32x4 o[4] = {};
#pragma unroll
    for (int c = 0; c < 9; ++c) {
        bf16x8 pf = *(const bf16x8*)&Ps[wave][l16][c * 32 + quad * 8];
#pragma unroll
        for (int j = 0; j < 4; ++j) {
            const bf16* vp = Vt + (size_t)(kh * 64 + j * 16 + l16) * VT_LD + lo + c * 32 + quad * 8;
            bf16x8 vf = *(const bf16x8*)vp;
            o[j] = __builtin_amdgcn_mfma_f32_16x16x32_bf16(pf, vf, o[j], 0, 0, 0);
        }
    }

#pragma unroll
    for (int j = 0; j < 4; ++j)
#pragma unroll
        for (int r = 0; r < 4; ++r)
            Oa[(size_t)(q0 + quad * 4 + r) * D_MODEL + h * 64 + j * 16 + l16] = (bf16)o[j][r];
}

// ---------------- launch ----------------

extern "C" void kernel_launch(void* const* d_in, const int* in_sizes, int n_in,
                              void* d_out, int out_size, void* d_ws, size_t ws_size,
                              hipStream_t stream) {
    const float* x  = (const float*)d_in[0];
    const float* Wq = (const float*)d_in[1];
    const float* bq = (const float*)d_in[2];
    const float* Wk = (const float*)d_in[3];
    const float* bk = (const float*)d_in[4];
    const float* Wv = (const float*)d_in[5];
    const float* bv = (const float*)d_in[6];
    const float* Wo = (const float*)d_in[7];
    const float* bo = (const float*)d_in[8];
    float* out = (float*)d_out;

    char* ws = (char*)d_ws;
    bf16*  xb    = (bf16*)(ws);                    // 4096x1024 bf16   (8 MB)
    bf16*  WtQKV = (bf16*)(ws + 8388608);          // 1536x1024 bf16   (3 MB)
    bf16*  WtO   = (bf16*)(ws + 11534336);         // 1024x1024 bf16   (2 MB)
    bf16*  QKV   = (bf16*)(ws + 13637632);         // 4096x1536 bf16   (12 MB; V region unused)
    bf16*  Vt    = (bf16*)(ws + 26220544);         // 256xVT_LD bf16   (~2 MB)
    bf16*  AO    = (bf16*)(ws + 28334080);         // 4096x1024 bf16   (8 MB) -> end ~35 MB

    prep_fused<<<4608, 256, 0, stream>>>(x, Wq, Wk, Wv, Wo, xb, WtQKV, WtO);

    gemm_bt<true, true><<<384, 256, 0, stream>>>(
        xb, WtQKV, bq, bk, bv, QKV, Vt, 4096, 1536, 12, 4);

    attn_kernel<<<dim3(64, 16), 256, 0, stream>>>(QKV, Vt, AO);

    gemm_bt<false, false><<<256, 256, 0, stream>>>(
        AO, WtO, bo, nullptr, nullptr, out, nullptr, 4096, 1024, 8, 4);
}

// Round 9
// 171.353 us; speedup vs baseline: 1.3304x; 1.3304x over previous
//
#include <hip/hip_runtime.h>

typedef __bf16 bf16;
typedef __bf16 bf16x4 __attribute__((ext_vector_type(4)));
typedef __bf16 bf16x8 __attribute__((ext_vector_type(8)));
typedef float f32x4 __attribute__((ext_vector_type(4)));

#define T_LEN   4096
#define D_MODEL 1024
#define QKV_LD  1536
#define VT_LD   4128   // 4096 + 32 pad: last tile's PV chunk over-reads into pad (x0 P)
#define WINDOW  256

// async global->LDS, 16 B per lane; data lands at readfirstlane(l) + lane*16
__device__ __forceinline__ void gload_lds16(const bf16* g, bf16* l) {
    __builtin_amdgcn_global_load_lds((const __attribute__((address_space(1))) void*)g,
                                     (__attribute__((address_space(3))) void*)l, 16, 0, 0);
}

// ---------------- fused prep: x->bf16, Wq|Wk|Wv transpose, Wo transpose -----
// grid sections: [0,2048) cvt, [2048,3584) wqkv, [3584,4608) wo

__global__ __launch_bounds__(256) void prep_fused(
    const float* __restrict__ x,
    const float* __restrict__ Wq, const float* __restrict__ Wk,
    const float* __restrict__ Wv, const float* __restrict__ Wo,
    bf16* __restrict__ xb, bf16* __restrict__ WtQKV, bf16* __restrict__ WtO)
{
    __shared__ float t[32][33];
    const int blk = blockIdx.x;
    if (blk < 2048) {                       // ---- x (f32) -> xb (bf16)
        int i = (blk * 256 + threadIdx.x) * 8;
        float4 a = *(const float4*)(x + i);
        float4 b = *(const float4*)(x + i + 4);
        bf16x8 o;
        o[0] = (bf16)a.x; o[1] = (bf16)a.y; o[2] = (bf16)a.z; o[3] = (bf16)a.w;
        o[4] = (bf16)b.x; o[5] = (bf16)b.y; o[6] = (bf16)b.z; o[7] = (bf16)b.w;
        *(bf16x8*)(xb + i) = o;
        return;
    }
    const float* W; bf16* Wt; int n0, k0, Ns, nofs;
    if (blk < 3584) {                       // ---- Wq|Wk|Wv -> WtQKV (1536x1024)
        int b = blk - 2048;
        n0 = (b % 48) * 32; k0 = (b / 48) * 32;
        if (n0 < 1024)      { W = Wq; Ns = 1024; nofs = 0; }
        else if (n0 < 1280) { W = Wk; Ns = 256;  nofs = 1024; }
        else                { W = Wv; Ns = 256;  nofs = 1280; }
        Wt = WtQKV;
    } else {                                // ---- Wo -> WtO (1024x1024)
        int b = blk - 3584;
        n0 = (b % 32) * 32; k0 = (b / 32) * 32;
        W = Wo; Ns = 1024; nofs = 0; Wt = WtO;
    }
    int tx = threadIdx.x & 31, ty = threadIdx.x >> 5;
#pragma unroll
    for (int it = 0; it < 4; ++it)
        t[ty + it * 8][tx] = W[(size_t)(k0 + ty + it * 8) * Ns + (n0 - nofs) + tx];
    __syncthreads();
#pragma unroll
    for (int it = 0; it < 4; ++it)
        Wt[(size_t)(n0 + ty + it * 8) * 1024 + k0 + tx] = (bf16)t[tx][ty + it * 8];
}

// ---------------- GEMM: C(MxN) = A(MxK)*Bt(NxK)^T + bias ----------------
// SMALL-TILE / HIGH-CO-RESIDENCY variant (m102: >=4 independent K-loop
// streams per CU is the regime where the m97 structure jumps 320->833 TF).
// 128 threads = 2 waves; block tile 64x64, wave tile 64x32 (acc 4x2).
// LDS 3 x (4KB A + 4KB B) = 24 KB -> 6 blocks/CU. 3-buffer pipeline, raw
// s_barrier + partial vmcnt. Staging: 256 16B-segs per tile-pair; each
// thread 2 A-segs + 2 B-segs per iter (wave-inst lands contiguous:
// base + lane*16). XCD swizzle: blk&7 = XCD, bands pinned per XCD.
// QKV_BIAS: col-blocks n0>=1280 are V -> written transposed to Vt.

template <bool OUT_BF16, bool QKV_BIAS>
__global__ __launch_bounds__(128) void gemm_bt(
    const bf16* __restrict__ A, const bf16* __restrict__ Bt,
    const float* __restrict__ b0, const float* __restrict__ b1,
    const float* __restrict__ b2, void* __restrict__ Cv, bf16* __restrict__ Vt,
    int M, int N, int K, int nbx, int bands_per_xcd)
{
    __shared__ bf16 As[3][64 * 32];
    __shared__ bf16 Bs[3][64 * 32];
    const int blk = blockIdx.x;
    const int xcd = blk & 7;
    const int s   = blk >> 3;
    const int m0 = (xcd * bands_per_xcd + s / nbx) * 64;
    const int n0 = (s % nbx) * 64;
    const int tid  = threadIdx.x;
    const int w    = tid >> 6, lane = tid & 63;
    const int quad = lane >> 4, l16 = lane & 15;

    f32x4 acc[4][2] = {};

    // staging: seg id in [0,256) per operand tile; 16 B per seg
    const int segA0 = w * 128 + lane;          // inst t=0
    const int segA1 = w * 128 + 64 + lane;     // inst t=1
    const bf16* gA0 = A  + (size_t)(m0 + (segA0 >> 2)) * K + (segA0 & 3) * 8;
    const bf16* gA1 = A  + (size_t)(m0 + (segA1 >> 2)) * K + (segA1 & 3) * 8;
    const bf16* gB0 = Bt + (size_t)(n0 + (segA0 >> 2)) * K + (segA0 & 3) * 8;
    const bf16* gB1 = Bt + (size_t)(n0 + (segA1 >> 2)) * K + (segA1 & 3) * 8;
    const int dA0 = segA0 * 8, dA1 = segA1 * 8;   // element offsets in LDS tile

    int bc = 0, bn = 1, bo = 2;   // current / next / overwrite buffer ids

    // prologue: stage kt=0 -> buf0, kt=1 -> buf1 (8 wave-loads in flight)
    gload_lds16(gA0,      &As[0][0] + dA0);
    gload_lds16(gA1,      &As[0][0] + dA1);
    gload_lds16(gB0,      &Bs[0][0] + dA0);
    gload_lds16(gB1,      &Bs[0][0] + dA1);
    gload_lds16(gA0 + 32, &As[1][0] + dA0);
    gload_lds16(gA1 + 32, &As[1][0] + dA1);
    gload_lds16(gB0 + 32, &Bs[1][0] + dA0);
    gload_lds16(gB1 + 32, &Bs[1][0] + dA1);

    const int raoff = l16 * 32 + quad * 8;               // A frag base (row i*16+l16)
    const int rboff = (w * 32 + l16) * 32 + quad * 8;    // B frag base (col w*32+j*16+l16)

    const int nk = K >> 5;
    for (int kt = 0; kt < nk; ++kt) {
        if (kt + 1 < nk) asm volatile("s_waitcnt vmcnt(4)" ::: "memory");
        else             asm volatile("s_waitcnt vmcnt(0)" ::: "memory");
        asm volatile("s_barrier" ::: "memory");
        if (kt + 2 < nk) {
            gload_lds16(gA0 + (kt + 2) * 32, &As[bo][0] + dA0);
            gload_lds16(gA1 + (kt + 2) * 32, &As[bo][0] + dA1);
            gload_lds16(gB0 + (kt + 2) * 32, &Bs[bo][0] + dA0);
            gload_lds16(gB1 + (kt + 2) * 32, &Bs[bo][0] + dA1);
        }
        const bf16* Ac = &As[bc][0];
        const bf16* Bc = &Bs[bc][0];
        bf16x8 af[4], bfr[2];
#pragma unroll
        for (int i = 0; i < 4; ++i)
            af[i] = *(const bf16x8*)(Ac + raoff + i * 16 * 32);
#pragma unroll
        for (int j = 0; j < 2; ++j)
            bfr[j] = *(const bf16x8*)(Bc + rboff + j * 16 * 32);
#pragma unroll
        for (int i = 0; i < 4; ++i)
#pragma unroll
            for (int j = 0; j < 2; ++j)
                acc[i][j] = __builtin_amdgcn_mfma_f32_16x16x32_bf16(af[i], bfr[j], acc[i][j], 0, 0, 0);
        int t = bc; bc = bn; bn = bo; bo = t;
    }

    const bool vtile = QKV_BIAS && (n0 >= 1280);
#pragma unroll
    for (int i = 0; i < 4; ++i)
#pragma unroll
        for (int j = 0; j < 2; ++j) {
            const int col = n0 + w * 32 + j * 16 + l16;
            const float bb = QKV_BIAS
                ? (col < 1024 ? b0[col] : (col < 1280 ? b1[col - 1024] : b2[col - 1280]))
                : b0[col];
            const int row0 = m0 + i * 16 + quad * 4;
            if (vtile) {
                bf16x4 pv;
#pragma unroll
                for (int r = 0; r < 4; ++r) pv[r] = (bf16)(acc[i][j][r] + bb);
                *(bf16x4*)&Vt[(size_t)(col - 1280) * VT_LD + row0] = pv;
            } else {
#pragma unroll
                for (int r = 0; r < 4; ++r) {
                    const float v = acc[i][j][r] + bb;
                    if (OUT_BF16) ((bf16*)Cv)[(size_t)(row0 + r) * N + col] = (bf16)v;
                    else          ((float*)Cv)[(size_t)(row0 + r) * N + col] = v;
                }
            }
        }
}

// ---------------- attention: 4 waves/block, 1 wave per (16-query tile, head) --
// Window <= 272 keys -> 17 S tiles of 16, PV over 9 K-chunks of 32.

__global__ __launch_bounds__(256) void attn_kernel(
    const bf16* __restrict__ QKV, const bf16* __restrict__ Vt, bf16* __restrict__ Oa)
{
    __shared__ bf16 Ps[4][16][296];   // per-wave P tile; 592 B rows: 2-way alias only
    const int wave = threadIdx.x >> 6;
    const int lane = threadIdx.x & 63;
    const int q0 = (blockIdx.x * 4 + wave) * 16;
    const int h  = blockIdx.y;
    const int kh = h >> 2;                     // GQA: head h -> kv head h/4
    const int quad = lane >> 4, l16 = lane & 15;
    const float slope = exp2f(-0.5f * (float)(h + 1));   // NH=16 ALiBi slopes
    const int lo = (q0 >= 256) ? (q0 - 256) : 0;          // window start

    // Q A-fragments (k-chunks 0 and 32 of HD=64)
    const bf16* qp = QKV + (size_t)(q0 + l16) * QKV_LD + h * 64 + quad * 8;
    bf16x8 qf0 = *(const bf16x8*)qp;
    bf16x8 qf1 = *(const bf16x8*)(qp + 32);

    // S = Q K^T : 17 tiles of 16 keys, fully unrolled so s[] stays in VGPRs
    f32x4 s[17];
#pragma unroll
    for (int t = 0; t < 17; ++t) {
        const bf16* kp = QKV + (size_t)(lo + t * 16 + l16) * QKV_LD + D_MODEL + kh * 64 + quad * 8;
        bf16x8 kf0 = *(const bf16x8*)kp;
        bf16x8 kf1 = *(const bf16x8*)(kp + 32);
        f32x4 a = {};
        a = __builtin_amdgcn_mfma_f32_16x16x32_bf16(qf0, kf0, a, 0, 0, 0);
        a = __builtin_amdgcn_mfma_f32_16x16x32_bf16(qf1, kf1, a, 0, 0, 0);
        s[t] = a;
    }

    // masked ALiBi softmax; lane holds rows quad*4+r at col l16 of each tile
    float rinv[4];
#pragma unroll
    for (int r = 0; r < 4; ++r) {
        const int row = q0 + quad * 4 + r;
        float mx = -1e30f;
#pragma unroll
        for (int t = 0; t < 17; ++t) {
            const int key = lo + t * 16 + l16;
            float v = s[t][r] * 0.125f - slope * (float)(row - key);
            const bool ok = (key <= row) && (key > row - WINDOW);
            v = ok ? v : -1e30f;
            s[t][r] = v;
            mx = fmaxf(mx, v);
        }
#pragma unroll
        for (int d = 1; d < 16; d <<= 1) mx = fmaxf(mx, __shfl_xor(mx, d));
        float sum = 0.f;
#pragma unroll
        for (int t = 0; t < 17; ++t) {
            float p = __expf(s[t][r] - mx);
            s[t][r] = p;
            sum += p;
        }
#pragma unroll
        for (int d = 1; d < 16; d <<= 1) sum += __shfl_xor(sum, d);
        rinv[r] = 1.f / sum;
    }

    // zero pad cols [272,288) (PV reads 288 cols)
    {
        int idx = lane;
#pragma unroll
        for (int it = 0; it < 4; ++it) {
            Ps[wave][(idx >> 4) & 15][272 + (idx & 15)] = (bf16)0.f;
            idx += 64;
        }
    }
    // P: C-layout regs -> LDS -> A-layout frags
#pragma unroll
    for (int t = 0; t < 17; ++t)
#pragma unroll
        for (int r = 0; r < 4; ++r)
            Ps[wave][quad * 4 + r][t * 16 + l16] = (bf16)(s[t][r] * rinv[r]);
    __syncthreads();

    // O = P V : V B-frags straight from global Vt (contiguous along keys)
    f32x4 o[4] = {};
#pragma unroll
    for (int c = 0; c < 9; ++c) {
        bf16x8 pf = *(const bf16x8*)&Ps[wave][l16][c * 32 + quad * 8];
#pragma unroll
        for (int j = 0; j < 4; ++j) {
            const bf16* vp = Vt + (size_t)(kh * 64 + j * 16 + l16) * VT_LD + lo + c * 32 + quad * 8;
            bf16x8 vf = *(const bf16x8*)vp;
            o[j] = __builtin_amdgcn_mfma_f32_16x16x32_bf16(pf, vf, o[j], 0, 0, 0);
        }
    }

#pragma unroll
    for (int j = 0; j < 4; ++j)
#pragma unroll
        for (int r = 0; r < 4; ++r)
            Oa[(size_t)(q0 + quad * 4 + r) * D_MODEL + h * 64 + j * 16 + l16] = (bf16)o[j][r];
}

// ---------------- launch ----------------

extern "C" void kernel_launch(void* const* d_in, const int* in_sizes, int n_in,
                              void* d_out, int out_size, void* d_ws, size_t ws_size,
                              hipStream_t stream) {
    const float* x  = (const float*)d_in[0];
    const float* Wq = (const float*)d_in[1];
    const float* bq = (const float*)d_in[2];
    const float* Wk = (const float*)d_in[3];
    const float* bk = (const float*)d_in[4];
    const float* Wv = (const float*)d_in[5];
    const float* bv = (const float*)d_in[6];
    const float* Wo = (const float*)d_in[7];
    const float* bo = (const float*)d_in[8];
    float* out = (float*)d_out;

    char* ws = (char*)d_ws;
    bf16*  xb    = (bf16*)(ws);                    // 4096x1024 bf16   (8 MB)
    bf16*  WtQKV = (bf16*)(ws + 8388608);          // 1536x1024 bf16   (3 MB)
    bf16*  WtO   = (bf16*)(ws + 11534336);         // 1024x1024 bf16   (2 MB)
    bf16*  QKV   = (bf16*)(ws + 13637632);         // 4096x1536 bf16   (12 MB; V region unused)
    bf16*  Vt    = (bf16*)(ws + 26220544);         // 256xVT_LD bf16   (~2 MB)
    bf16*  AO    = (bf16*)(ws + 28334080);         // 4096x1024 bf16   (8 MB) -> end ~35 MB

    prep_fused<<<4608, 256, 0, stream>>>(x, Wq, Wk, Wv, Wo, xb, WtQKV, WtO);

    gemm_bt<true, true><<<1536, 128, 0, stream>>>(
        xb, WtQKV, bq, bk, bv, QKV, Vt, 4096, 1536, 1024, 24, 8);

    attn_kernel<<<dim3(64, 16), 256, 0, stream>>>(QKV, Vt, AO);

    gemm_bt<false, false><<<1024, 128, 0, stream>>>(
        AO, WtO, bo, nullptr, nullptr, out, nullptr, 4096, 1024, 1024, 16, 8);
}